// Round 2
// baseline (382.146 us; speedup 1.0000x reference)
//
#include <hip/hip_runtime.h>
#include <hip/hip_bf16.h>
#include <stdint.h>

#define SEQ 2048
#define DIM 64
#define NH  64          // B*H heads
#define KT  32          // keys per tile
#define NT  (SEQ / KT)  // 64 tiles per head
#define FRAG_BYTES 12288 // K hi/lo f16 (8KB) + V bf16 (4KB)
#define KF_BYTES   8192

typedef __attribute__((ext_vector_type(8)))  short    bf16x8;
typedef __attribute__((ext_vector_type(8)))  _Float16 f16x8;
typedef __attribute__((ext_vector_type(16))) float    f32x16;
typedef unsigned int u32;

#if __has_builtin(__builtin_amdgcn_exp2f)
#define EXP2(x) __builtin_amdgcn_exp2f(x)
#else
#define EXP2(x) exp2f(x)
#endif

// key permutation: slot s in the 32-key tile holds key phi(s) (softmax is
// permutation-invariant over keys; K rows and V k-index use the same phi)
__device__ __forceinline__ int phi(int s) {
    int h = (s >> 2) & 1, b = s >> 3, i = s & 3;
    return 8 * h + 4 * b + i + (b >= 2 ? 8 : 0);
}
__device__ __forceinline__ short f2bf(float f) {
    union { float f; u32 u; } v; v.f = f;
    u32 r = v.u + 0x7fffu + ((v.u >> 16) & 1u);
    return (short)(r >> 16);
}

__global__ __launch_bounds__(256, 3) void attn_fused(
    const float* __restrict__ Q, const float* __restrict__ K,
    const float* __restrict__ V, float* __restrict__ O)
{
    // frag double-buffer only (24KB) -> 3 blocks/CU (12 waves/CU)
    __shared__ __align__(16) char frag[2][FRAG_BYTES];

    const int tid  = threadIdx.x;
    const int wave = tid >> 6, lane = tid & 63;
    const int h = lane >> 5, col = lane & 31;

    // XCD swizzle: all 8 q-blocks of a head land on the same XCD
    // (512 blocks round-robin over 8 XCDs; swap the two 3-bit fields)
    const int bid  = blockIdx.x;
    const int head = (bid & 7) * 8 + ((bid >> 3) & 7);
    const int qb   = (bid >> 6) * 256 + wave * 64;   // 64 q rows per wave
    const size_t base = (size_t)head * SEQ * DIM;

    // ---- per-thread staging addresses (register staging, no raw LDS) ----
    // K role: this wave converts K[phi(col)][wave*16 + 8h + 0..7] (8 floats, 32B)
    const float* kbase = K + base + (size_t)phi(col) * DIM + wave * 16 + 8 * h;
    // V role: (fv,cv) per wave; 8 column-strided scalars V[phi(16cv+8h+j)][fv*32+col]
    const int fv = tid >> 7, cv = (tid >> 6) & 1;
    int vrow[8];
    #pragma unroll
    for (int j = 0; j < 8; ++j) vrow[j] = phi(16 * cv + 8 * h + j);
    const float* vbase = V + base + fv * 32 + col;

    float4 ka, kb; float vv[8];
    auto load_stage = [&](int kt) {   // issue early: latency hides under compute
        const float* kp = kbase + (size_t)kt * (KT * DIM);
        ka = *(const float4*)(kp);
        kb = *(const float4*)(kp + 4);
        const float* vp = vbase + (size_t)kt * (KT * DIM);
        #pragma unroll
        for (int j = 0; j < 8; ++j) vv[j] = vp[vrow[j] * DIM];
    };
    auto convert = [&](char* dst) {   // regs -> frag blob (same layout as before)
        float x[8] = {ka.x, ka.y, ka.z, ka.w, kb.x, kb.y, kb.z, kb.w};
        f16x8 hi, lo;
        #pragma unroll
        for (int j = 0; j < 8; ++j) {
            _Float16 xh = (_Float16)x[j];
            hi[j] = xh;
            lo[j] = (_Float16)(x[j] - (float)xh);
        }
        *(f16x8*)(dst + (wave * 2 + 0) * 1024 + lane * 16) = hi;
        *(f16x8*)(dst + (wave * 2 + 1) * 1024 + lane * 16) = lo;
        bf16x8 v;
        #pragma unroll
        for (int j = 0; j < 8; ++j) v[j] = f2bf(vv[j]);
        *(bf16x8*)(dst + KF_BYTES + (fv * 2 + cv) * 1024 + lane * 16) = v;
    };

    // Q B-frags f16, log2e folded in: B[k=c*16+8h+j][n=col]
    f16x8 qf[2][4];
    #pragma unroll
    for (int qt = 0; qt < 2; ++qt) {
        const float* qr = Q + base + (size_t)(qb + qt * 32 + col) * DIM;
        #pragma unroll
        for (int c = 0; c < 4; ++c)
            #pragma unroll
            for (int j = 0; j < 8; ++j)
                qf[qt][c][j] = (_Float16)(qr[c * 16 + 8 * h + j] * 1.44269504088896f);
    }

    f32x16 z16;
    #pragma unroll
    for (int r = 0; r < 16; ++r) z16[r] = 0.f;
    f32x16 of[2][2];
    of[0][0] = z16; of[0][1] = z16; of[1][0] = z16; of[1][1] = z16;
    float l_own[2] = {0.f, 0.f};

    // ---- pipeline prologue: tile 0 ----
    load_stage(0);
    convert(frag[0]);

    for (int kt = 0; kt < NT; ++kt) {
        __syncthreads();   // frag[kt&1] (written at end of kt-1) visible to all waves
        if (kt + 1 < NT)
            load_stage(kt + 1);          // regs for tile kt+1; in flight during compute
        const char* cur = frag[kt & 1];

        // S'^T[slot][q] = K.Q^T (log2 units), 2-term split precision
        f32x16 s[2]; s[0] = z16; s[1] = z16;
        #pragma unroll
        for (int c = 0; c < 4; ++c) {
            f16x8 kh = *(const f16x8*)(cur + (c * 2 + 0) * 1024 + lane * 16);
            f16x8 kl = *(const f16x8*)(cur + (c * 2 + 1) * 1024 + lane * 16);
            s[0] = __builtin_amdgcn_mfma_f32_32x32x16_f16(kh, qf[0][c], s[0], 0, 0, 0);
            s[0] = __builtin_amdgcn_mfma_f32_32x32x16_f16(kl, qf[0][c], s[0], 0, 0, 0);
            s[1] = __builtin_amdgcn_mfma_f32_32x32x16_f16(kh, qf[1][c], s[1], 0, 0, 0);
            s[1] = __builtin_amdgcn_mfma_f32_32x32x16_f16(kl, qf[1][c], s[1], 0, 0, 0);
        }

        // exp2, row-sum, pack to bf16, cross-half exchange -> P A-frags
        bf16x8 pfrag[2][2];
        #pragma unroll
        for (int qt = 0; qt < 2; ++qt) {
            float p[16], ls = 0.f;
            #pragma unroll
            for (int r = 0; r < 16; ++r) { p[r] = EXP2(s[qt][r]); ls += p[r]; }
            l_own[qt] += ls;
            u32 pk[8], sw[8];
            #pragma unroll
            for (int m = 0; m < 8; ++m) {
                __hip_bfloat162 b2 = __float22bfloat162_rn(make_float2(p[2 * m], p[2 * m + 1]));
                __builtin_memcpy(&pk[m], &b2, 4);
            }
            #pragma unroll
            for (int m = 0; m < 8; ++m) sw[m] = __shfl_xor(pk[m], 32);
            #pragma unroll
            for (int c = 0; c < 2; ++c) {
                union { u32 w[4]; bf16x8 v; } fr;
                fr.w[0] = h ? sw[4 * c + 2] : pk[4 * c + 0];
                fr.w[1] = h ? sw[4 * c + 3] : pk[4 * c + 1];
                fr.w[2] = h ? pk[4 * c + 2] : sw[4 * c + 0];
                fr.w[3] = h ? pk[4 * c + 3] : sw[4 * c + 1];
                pfrag[qt][c] = fr.v;
            }
        }

        // O[q][d] += P.V
        #pragma unroll
        for (int f = 0; f < 2; ++f)
            #pragma unroll
            for (int c = 0; c < 2; ++c) {
                bf16x8 vf = *(const bf16x8*)(cur + KF_BYTES + (f * 2 + c) * 1024 + lane * 16);
                of[0][f] = __builtin_amdgcn_mfma_f32_32x32x16_bf16(pfrag[0][c], vf, of[0][f], 0, 0, 0);
                of[1][f] = __builtin_amdgcn_mfma_f32_32x32x16_bf16(pfrag[1][c], vf, of[1][f], 0, 0, 0);
            }

        // convert tile kt+1 regs -> frag[(kt+1)&1] (that buffer was last read
        // in iter kt-1; the barrier at top of kt made everyone done with it)
        if (kt + 1 < NT)
            convert(frag[(kt + 1) & 1]);
    }

    // Epilogue: O /= l
    float* op = O + base;
    #pragma unroll
    for (int qt = 0; qt < 2; ++qt) {
        float lall = l_own[qt] + __shfl_xor(l_own[qt], 32);  // both halves of q=col
        float inv = 1.0f / lall;
        #pragma unroll
        for (int r = 0; r < 16; ++r) {
            int qrow = (r & 3) + 8 * (r >> 2) + 4 * h;
            float iq = __shfl(inv, qrow);
            op[(size_t)(qb + qt * 32 + qrow) * DIM + col]      = of[qt][0][r] * iq;
            op[(size_t)(qb + qt * 32 + qrow) * DIM + 32 + col] = of[qt][1][r] * iq;
        }
    }
}

extern "C" void kernel_launch(void* const* d_in, const int* in_sizes, int n_in,
                              void* d_out, int out_size, void* d_ws, size_t ws_size,
                              hipStream_t stream) {
    const float* Q = (const float*)d_in[0];
    const float* K = (const float*)d_in[1];
    const float* V = (const float*)d_in[2];
    float* Out = (float*)d_out;
    (void)d_ws; (void)ws_size;

    attn_fused<<<dim3(NH * (SEQ / 256)), dim3(256), 0, stream>>>(Q, K, V, Out);
}

// Round 3
// 244.496 us; speedup vs baseline: 1.5630x; 1.5630x over previous
//
#include <hip/hip_runtime.h>
#include <hip/hip_bf16.h>
#include <stdint.h>

#define SEQ 2048
#define DIM 64
#define NH  64          // B*H heads
#define KT  32          // keys per tile
#define NT  (SEQ / KT)  // 64 tiles per head
#define RAW_BYTES  16384 // fp32 K tile (8KB) + fp32 V tile (8KB)
#define FRAG_BYTES 12288 // K hi/lo f16 (8KB) + V bf16 (4KB)
#define KF_BYTES   8192

typedef __attribute__((ext_vector_type(8)))  short    bf16x8;
typedef __attribute__((ext_vector_type(8)))  _Float16 f16x8;
typedef __attribute__((ext_vector_type(16))) float    f32x16;
typedef unsigned int u32;

#if __has_builtin(__builtin_amdgcn_exp2f)
#define EXP2(x) __builtin_amdgcn_exp2f(x)
#else
#define EXP2(x) exp2f(x)
#endif

// key permutation: slot s in the 32-key tile holds key phi(s) (softmax is
// permutation-invariant over keys; K rows and V k-index use the same phi)
__device__ __forceinline__ int phi(int s) {
    int h = (s >> 2) & 1, b = s >> 3, i = s & 3;
    return 8 * h + 4 * b + i + (b >= 2 ? 8 : 0);
}
__device__ __forceinline__ short f2bf(float f) {
    union { float f; u32 u; } v; v.f = f;
    u32 r = v.u + 0x7fffu + ((v.u >> 16) & 1u);
    return (short)(r >> 16);
}

// async global->LDS staging of one raw fp32 tile (K 8KB + V 8KB), 4 glds/lane.
// K source is chunk-swizzled (pos = k ^ (row&7)) so the conversion's
// row-major 32B reads are bank-conflict-free; LDS dest stays linear.
__device__ __forceinline__ void stage_tile(const float* gK, const float* gV,
                                           char* raw, int wave, int lane) {
    #pragma unroll
    for (int i = 0; i < 2; ++i) {
        const int P  = wave * 128 + i * 64 + lane;              // 16B-chunk id
        const int sk = (P & ~15) | ((P & 15) ^ ((P >> 4) & 7)); // swizzled K src chunk
        char* dK = raw + (size_t)(wave * 128 + i * 64) * 16;        // wave-uniform
        char* dV = raw + 8192 + (size_t)(wave * 128 + i * 64) * 16; // wave-uniform
        __builtin_amdgcn_global_load_lds(
            (const __attribute__((address_space(1))) u32*)((const char*)gK + (size_t)sk * 16),
            (__attribute__((address_space(3))) u32*)dK, 16, 0, 0);
        __builtin_amdgcn_global_load_lds(
            (const __attribute__((address_space(1))) u32*)((const char*)gV + (size_t)P * 16),
            (__attribute__((address_space(3))) u32*)dV, 16, 0, 0);
    }
}

// block-cooperative raw fp32 tile -> MFMA fragment blob
//   [4c x {Khi,Klo} x 64lane x 8 f16] (8KB) then [2f x 2c x 64lane x 8 bf16] (4KB)
__device__ __forceinline__ void convert_tile(const char* raw, char* frag, int t) {
    const int lane = t & 63, col = lane & 31, h = lane >> 5;
    {   // K frags: A[m=slot=col][k=d], split f16 hi/lo
        const int c = t >> 6;
        const int r = phi(col);
        const int kk = 4 * c + 2 * h;
        const float4* rk = (const float4*)raw;
        float4 a = rk[r * 16 + ((kk    ) ^ (r & 7))];
        float4 b = rk[r * 16 + ((kk + 1) ^ (r & 7))];
        float x[8] = {a.x, a.y, a.z, a.w, b.x, b.y, b.z, b.w};
        f16x8 hi, lo;
        #pragma unroll
        for (int j = 0; j < 8; ++j) {
            _Float16 xh = (_Float16)x[j];
            hi[j] = xh;
            lo[j] = (_Float16)(x[j] - (float)xh);
        }
        *(f16x8*)(frag + (c * 2 + 0) * 1024 + lane * 16) = hi;
        *(f16x8*)(frag + (c * 2 + 1) * 1024 + lane * 16) = lo;
    }
    {   // V frags: B[k=slot][n=d]
        const int f = t >> 7, c = (t >> 6) & 1;
        const float* rv = (const float*)(raw + 8192);
        bf16x8 v;
        #pragma unroll
        for (int j = 0; j < 8; ++j) {
            int key = phi(16 * c + 8 * h + j);
            v[j] = f2bf(rv[key * 64 + f * 32 + col]); // bank=col -> conflict-free
        }
        *(bf16x8*)(frag + KF_BYTES + (f * 2 + c) * 1024 + lane * 16) = v;
    }
}

__global__ __launch_bounds__(256, 2) void attn_fused(
    const float* __restrict__ Q, const float* __restrict__ K,
    const float* __restrict__ V, float* __restrict__ O)
{
    __shared__ __align__(16) char raw[3][RAW_BYTES];    // fp32 staging, 3-deep
    __shared__ __align__(16) char frag[2][FRAG_BYTES];  // MFMA frag blob, dbuf

    const int tid  = threadIdx.x;
    const int wave = tid >> 6, lane = tid & 63;
    const int h = lane >> 5, col = lane & 31;

    // XCD swizzle: all 8 q-blocks of a head land on the same XCD (bijective,
    // 512 blocks all co-resident at 2 blocks/CU -> K/V hit local L2)
    const int bid  = blockIdx.x;
    const int head = (bid & 7) * 8 + ((bid >> 3) & 7);
    const int qb   = (bid >> 6) * 256 + wave * 64;   // 64 q rows per wave
    const size_t base = (size_t)head * SEQ * DIM;
    const float* Kh = K + base;
    const float* Vh = V + base;

    // Q B-frags f16, log2e folded in: B[k=c*16+8h+j][n=col]  (issued first so
    // the prologue vmcnt counts only glds above the waited threshold)
    f16x8 qf[2][4];
    #pragma unroll
    for (int qt = 0; qt < 2; ++qt) {
        const float* qr = Q + base + (size_t)(qb + qt * 32 + col) * DIM;
        #pragma unroll
        for (int c = 0; c < 4; ++c)
            #pragma unroll
            for (int j = 0; j < 8; ++j)
                qf[qt][c][j] = (_Float16)(qr[c * 16 + 8 * h + j] * 1.44269504088896f);
    }

    f32x16 z16;
    #pragma unroll
    for (int r = 0; r < 16; ++r) z16[r] = 0.f;
    f32x16 of[2][2];
    of[0][0] = z16; of[0][1] = z16; of[1][0] = z16; of[1][1] = z16;
    float l_own[2] = {0.f, 0.f};

    // ---- pipeline prologue: tiles 0,1 in flight; convert tile 0 ----
    stage_tile(Kh, Vh, raw[0], wave, lane);                        // 4 glds
    stage_tile(Kh + KT * DIM, Vh + KT * DIM, raw[1], wave, lane);  // 4 glds
    asm volatile("s_waitcnt vmcnt(4)" ::: "memory");   // tile 0 landed
    __builtin_amdgcn_s_barrier();
    __builtin_amdgcn_sched_barrier(0);
    convert_tile(raw[0], frag[0], tid);

    int stg_i = 2;  // raw index receiving tile kt+2
    int cvt_i = 1;  // raw index holding tile kt+1

    for (int kt = 0; kt < NT; ++kt) {
        // barrier A: my frag ds_writes drained, then all waves aligned ->
        // frag[kt&1] visible; glds for kt+1/kt+2 stay in flight (no vmcnt0!)
        asm volatile("s_waitcnt lgkmcnt(0)" ::: "memory");
        __builtin_amdgcn_s_barrier();
        __builtin_amdgcn_sched_barrier(0);

        if (kt + 2 < NT)
            stage_tile(Kh + (size_t)(kt + 2) * KT * DIM,
                       Vh + (size_t)(kt + 2) * KT * DIM, raw[stg_i], wave, lane);
        const char* cur = frag[kt & 1];

        // S'^T[slot][q] = K.Q^T (log2 units), 2-term split precision
        f32x16 s[2]; s[0] = z16; s[1] = z16;
        __builtin_amdgcn_s_setprio(1);
        #pragma unroll
        for (int c = 0; c < 4; ++c) {
            f16x8 kh = *(const f16x8*)(cur + (c * 2 + 0) * 1024 + lane * 16);
            f16x8 kl = *(const f16x8*)(cur + (c * 2 + 1) * 1024 + lane * 16);
            s[0] = __builtin_amdgcn_mfma_f32_32x32x16_f16(kh, qf[0][c], s[0], 0, 0, 0);
            s[0] = __builtin_amdgcn_mfma_f32_32x32x16_f16(kl, qf[0][c], s[0], 0, 0, 0);
            s[1] = __builtin_amdgcn_mfma_f32_32x32x16_f16(kh, qf[1][c], s[1], 0, 0, 0);
            s[1] = __builtin_amdgcn_mfma_f32_32x32x16_f16(kl, qf[1][c], s[1], 0, 0, 0);
        }
        __builtin_amdgcn_s_setprio(0);

        // exp2, row-sum, pack to bf16, cross-half exchange -> P A-frags
        bf16x8 pfrag[2][2];
        #pragma unroll
        for (int qt = 0; qt < 2; ++qt) {
            float p[16], ls = 0.f;
            #pragma unroll
            for (int r = 0; r < 16; ++r) { p[r] = EXP2(s[qt][r]); ls += p[r]; }
            l_own[qt] += ls;
            u32 pk[8], sw[8];
            #pragma unroll
            for (int m = 0; m < 8; ++m) {
                __hip_bfloat162 b2 = __float22bfloat162_rn(make_float2(p[2 * m], p[2 * m + 1]));
                __builtin_memcpy(&pk[m], &b2, 4);
            }
            #pragma unroll
            for (int m = 0; m < 8; ++m) sw[m] = __shfl_xor(pk[m], 32);
            #pragma unroll
            for (int c = 0; c < 2; ++c) {
                union { u32 w[4]; bf16x8 v; } fr;
                fr.w[0] = h ? sw[4 * c + 2] : pk[4 * c + 0];
                fr.w[1] = h ? sw[4 * c + 3] : pk[4 * c + 1];
                fr.w[2] = h ? pk[4 * c + 2] : sw[4 * c + 0];
                fr.w[3] = h ? pk[4 * c + 3] : sw[4 * c + 1];
                pfrag[qt][c] = fr.v;
            }
        }

        // O[q][d] += P.V
        __builtin_amdgcn_s_setprio(1);
        #pragma unroll
        for (int f = 0; f < 2; ++f)
            #pragma unroll
            for (int c = 0; c < 2; ++c) {
                bf16x8 vf = *(const bf16x8*)(cur + KF_BYTES + (f * 2 + c) * 1024 + lane * 16);
                of[0][f] = __builtin_amdgcn_mfma_f32_32x32x16_bf16(pfrag[0][c], vf, of[0][f], 0, 0, 0);
                of[1][f] = __builtin_amdgcn_mfma_f32_32x32x16_bf16(pfrag[1][c], vf, of[1][f], 0, 0, 0);
            }
        __builtin_amdgcn_s_setprio(0);

        // barrier B: tile kt+1's glds landed (counted wait -- kt+2's 4 glds
        // stay in flight), then convert it into the other frag buffer
        if (kt + 1 < NT) {
            if (kt + 2 < NT) asm volatile("s_waitcnt vmcnt(4)" ::: "memory");
            else             asm volatile("s_waitcnt vmcnt(0)" ::: "memory");
            __builtin_amdgcn_s_barrier();
            __builtin_amdgcn_sched_barrier(0);
            convert_tile(raw[cvt_i], frag[(kt + 1) & 1], tid);
        }
        stg_i = (stg_i == 2) ? 0 : stg_i + 1;
        cvt_i = (cvt_i == 2) ? 0 : cvt_i + 1;
    }

    // Epilogue: O /= l
    float* op = O + base;
    #pragma unroll
    for (int qt = 0; qt < 2; ++qt) {
        float lall = l_own[qt] + __shfl_xor(l_own[qt], 32);  // both halves of q=col
        float inv = 1.0f / lall;
        #pragma unroll
        for (int r = 0; r < 16; ++r) {
            int qrow = (r & 3) + 8 * (r >> 2) + 4 * h;
            float iq = __shfl(inv, qrow);
            op[(size_t)(qb + qt * 32 + qrow) * DIM + col]      = of[qt][0][r] * iq;
            op[(size_t)(qb + qt * 32 + qrow) * DIM + 32 + col] = of[qt][1][r] * iq;
        }
    }
}

extern "C" void kernel_launch(void* const* d_in, const int* in_sizes, int n_in,
                              void* d_out, int out_size, void* d_ws, size_t ws_size,
                              hipStream_t stream) {
    const float* Q = (const float*)d_in[0];
    const float* K = (const float*)d_in[1];
    const float* V = (const float*)d_in[2];
    float* Out = (float*)d_out;
    (void)d_ws; (void)ws_size;

    attn_fused<<<dim3(NH * (SEQ / 256)), dim3(256), 0, stream>>>(Q, K, V, Out);
}

// Round 4
// 231.766 us; speedup vs baseline: 1.6488x; 1.0549x over previous
//
#include <hip/hip_runtime.h>
#include <hip/hip_bf16.h>
#include <stdint.h>

#define SEQ 2048
#define DIM 64
#define NH  64          // B*H heads
#define KT  32          // keys per tile
#define NT  (SEQ / KT)  // 64 tiles per head
#define RAW_BYTES  16384 // fp32 K tile (8KB) + fp32 V tile (8KB)
#define FRAG_BYTES 12288 // K hi/lo f16 (8KB) + V bf16 (4KB)
#define KF_BYTES   8192

typedef __attribute__((ext_vector_type(8)))  short    bf16x8;
typedef __attribute__((ext_vector_type(8)))  _Float16 f16x8;
typedef __attribute__((ext_vector_type(16))) float    f32x16;
typedef unsigned int u32;

#if __has_builtin(__builtin_amdgcn_exp2f)
#define EXP2(x) __builtin_amdgcn_exp2f(x)
#else
#define EXP2(x) exp2f(x)
#endif

// key permutation: slot s in the 32-key tile holds key phi(s) (softmax is
// permutation-invariant over keys; K rows and V k-index use the same phi)
__device__ __forceinline__ int phi(int s) {
    int h = (s >> 2) & 1, b = s >> 3, i = s & 3;
    return 8 * h + 4 * b + i + (b >= 2 ? 8 : 0);
}
__device__ __forceinline__ short f2bf(float f) {
    union { float f; u32 u; } v; v.f = f;
    u32 r = v.u + 0x7fffu + ((v.u >> 16) & 1u);
    return (short)(r >> 16);
}

// async global->LDS staging of one raw fp32 tile (K 8KB + V 8KB).
// 512 threads: each lane issues 1 K-glds + 1 V-glds (2 vmem/lane/tile).
// K source is chunk-swizzled (pos = k ^ (row&7)) so the conversion's
// row-major 32B reads are bank-conflict-free; LDS dest stays linear.
__device__ __forceinline__ void stage_tile(const float* gK, const float* gV,
                                           char* raw, int wave, int lane) {
    const int P  = wave * 64 + lane;                        // 16B-chunk id, 0..511
    const int sk = (P & ~15) | ((P & 15) ^ ((P >> 4) & 7)); // swizzled K src chunk
    char* dK = raw + (size_t)(wave * 64) * 16;              // wave-uniform base
    char* dV = raw + 8192 + (size_t)(wave * 64) * 16;       // wave-uniform base
    __builtin_amdgcn_global_load_lds(
        (const __attribute__((address_space(1))) u32*)((const char*)gK + (size_t)sk * 16),
        (__attribute__((address_space(3))) u32*)dK, 16, 0, 0);
    __builtin_amdgcn_global_load_lds(
        (const __attribute__((address_space(1))) u32*)((const char*)gV + (size_t)P * 16),
        (__attribute__((address_space(3))) u32*)dV, 16, 0, 0);
}

// block-cooperative raw fp32 tile -> MFMA fragment blob
//   [4c x {Khi,Klo} x 64lane x 8 f16] (8KB) then [2f x 2c x 64lane x 8 bf16] (4KB)
// 512 threads: waves 0-3 convert K, waves 4-7 convert V (wave-uniform split).
__device__ __forceinline__ void convert_tile(const char* raw, char* frag, int t) {
    const int lane = t & 63, col = lane & 31, h = lane >> 5;
    if (t < 256) {   // K frags: A[m=slot=col][k=d], split f16 hi/lo
        const int c = t >> 6;
        const int r = phi(col);
        const int kk = 4 * c + 2 * h;
        const float4* rk = (const float4*)raw;
        float4 a = rk[r * 16 + ((kk    ) ^ (r & 7))];
        float4 b = rk[r * 16 + ((kk + 1) ^ (r & 7))];
        float x[8] = {a.x, a.y, a.z, a.w, b.x, b.y, b.z, b.w};
        f16x8 hi, lo;
        #pragma unroll
        for (int j = 0; j < 8; ++j) {
            _Float16 xh = (_Float16)x[j];
            hi[j] = xh;
            lo[j] = (_Float16)(x[j] - (float)xh);
        }
        *(f16x8*)(frag + (c * 2 + 0) * 1024 + lane * 16) = hi;
        *(f16x8*)(frag + (c * 2 + 1) * 1024 + lane * 16) = lo;
    } else {         // V frags: B[k=slot][n=d]
        const int u = t - 256;
        const int f = u >> 7, c = (u >> 6) & 1;
        const float* rv = (const float*)(raw + 8192);
        bf16x8 v;
        #pragma unroll
        for (int j = 0; j < 8; ++j) {
            int key = phi(16 * c + 8 * h + j);
            v[j] = f2bf(rv[key * 64 + f * 32 + col]); // bank=col -> conflict-free
        }
        *(bf16x8*)(frag + KF_BYTES + (f * 2 + c) * 1024 + lane * 16) = v;
    }
}

__global__ __launch_bounds__(512, 4) void attn_fused(
    const float* __restrict__ Q, const float* __restrict__ K,
    const float* __restrict__ V, float* __restrict__ O)
{
    __shared__ __align__(16) char raw[3][RAW_BYTES];    // fp32 staging, 3-deep
    __shared__ __align__(16) char frag[2][FRAG_BYTES];  // MFMA frag blob, dbuf

    const int tid  = threadIdx.x;
    const int wave = tid >> 6, lane = tid & 63;
    const int h = lane >> 5, col = lane & 31;

    // XCD swizzle: all 8 q-blocks of a head land on the same XCD (bijective,
    // 512 blocks all co-resident at 2 blocks/CU -> K/V hit local L2)
    const int bid  = blockIdx.x;
    const int head = (bid & 7) * 8 + ((bid >> 3) & 7);
    const int qw   = (bid >> 6) * 256 + wave * 32;   // 32 q rows per wave
    const size_t base = (size_t)head * SEQ * DIM;
    const float* Kh = K + base;
    const float* Vh = V + base;

    // Q B-frags f16, log2e folded in: B[k=c*16+8h+j][n=col]
    f16x8 qf[4];
    {
        const float* qr = Q + base + (size_t)(qw + col) * DIM;
        #pragma unroll
        for (int c = 0; c < 4; ++c)
            #pragma unroll
            for (int j = 0; j < 8; ++j)
                qf[c][j] = (_Float16)(qr[c * 16 + 8 * h + j] * 1.44269504088896f);
    }

    f32x16 z16;
    #pragma unroll
    for (int r = 0; r < 16; ++r) z16[r] = 0.f;
    f32x16 of[2];
    of[0] = z16; of[1] = z16;
    float l_own = 0.f;

    // ---- pipeline prologue: tiles 0,1 in flight; convert tile 0 ----
    stage_tile(Kh, Vh, raw[0], wave, lane);                        // 2 glds/lane
    stage_tile(Kh + KT * DIM, Vh + KT * DIM, raw[1], wave, lane);  // 2 glds/lane
    asm volatile("s_waitcnt vmcnt(2)" ::: "memory");   // tile 0 landed
    __builtin_amdgcn_s_barrier();
    __builtin_amdgcn_sched_barrier(0);
    convert_tile(raw[0], frag[0], tid);

    int stg_i = 2;  // raw index receiving tile kt+2
    int cvt_i = 1;  // raw index holding tile kt+1

    for (int kt = 0; kt < NT; ++kt) {
        // barrier A: my frag ds_writes drained, then all waves aligned ->
        // frag[kt&1] visible; glds for kt+1/kt+2 stay in flight (no vmcnt0!)
        asm volatile("s_waitcnt lgkmcnt(0)" ::: "memory");
        __builtin_amdgcn_s_barrier();
        __builtin_amdgcn_sched_barrier(0);

        if (kt + 2 < NT)
            stage_tile(Kh + (size_t)(kt + 2) * KT * DIM,
                       Vh + (size_t)(kt + 2) * KT * DIM, raw[stg_i], wave, lane);
        const char* cur = frag[kt & 1];

        // S'^T[slot][q] = K.Q^T (log2 units), 2-term split precision
        f32x16 s = z16;
        __builtin_amdgcn_s_setprio(1);
        #pragma unroll
        for (int c = 0; c < 4; ++c) {
            f16x8 kh = *(const f16x8*)(cur + (c * 2 + 0) * 1024 + lane * 16);
            f16x8 kl = *(const f16x8*)(cur + (c * 2 + 1) * 1024 + lane * 16);
            s = __builtin_amdgcn_mfma_f32_32x32x16_f16(kh, qf[c], s, 0, 0, 0);
            s = __builtin_amdgcn_mfma_f32_32x32x16_f16(kl, qf[c], s, 0, 0, 0);
        }
        __builtin_amdgcn_s_setprio(0);

        // exp2, row-sum, pack to bf16, cross-half exchange -> P A-frags
        bf16x8 pfrag[2];
        {
            float p[16], ls = 0.f;
            #pragma unroll
            for (int r = 0; r < 16; ++r) { p[r] = EXP2(s[r]); ls += p[r]; }
            l_own += ls;
            u32 pk[8], sw[8];
            #pragma unroll
            for (int m = 0; m < 8; ++m) {
                __hip_bfloat162 b2 = __float22bfloat162_rn(make_float2(p[2 * m], p[2 * m + 1]));
                __builtin_memcpy(&pk[m], &b2, 4);
            }
            #pragma unroll
            for (int m = 0; m < 8; ++m) sw[m] = __shfl_xor(pk[m], 32);
            #pragma unroll
            for (int c = 0; c < 2; ++c) {
                union { u32 w[4]; bf16x8 v; } fr;
                fr.w[0] = h ? sw[4 * c + 2] : pk[4 * c + 0];
                fr.w[1] = h ? sw[4 * c + 3] : pk[4 * c + 1];
                fr.w[2] = h ? pk[4 * c + 2] : sw[4 * c + 0];
                fr.w[3] = h ? pk[4 * c + 3] : sw[4 * c + 1];
                pfrag[c] = fr.v;
            }
        }

        // O[q][d] += P.V
        __builtin_amdgcn_s_setprio(1);
        #pragma unroll
        for (int f = 0; f < 2; ++f)
            #pragma unroll
            for (int c = 0; c < 2; ++c) {
                bf16x8 vf = *(const bf16x8*)(cur + KF_BYTES + (f * 2 + c) * 1024 + lane * 16);
                of[f] = __builtin_amdgcn_mfma_f32_32x32x16_bf16(pfrag[c], vf, of[f], 0, 0, 0);
            }
        __builtin_amdgcn_s_setprio(0);

        // barrier B: tile kt+1's glds landed (counted wait -- kt+2's 2 glds
        // stay in flight), then convert it into the other frag buffer
        if (kt + 1 < NT) {
            if (kt + 2 < NT) asm volatile("s_waitcnt vmcnt(2)" ::: "memory");
            else             asm volatile("s_waitcnt vmcnt(0)" ::: "memory");
            __builtin_amdgcn_s_barrier();
            __builtin_amdgcn_sched_barrier(0);
            convert_tile(raw[cvt_i], frag[(kt + 1) & 1], tid);
        }
        stg_i = (stg_i == 2) ? 0 : stg_i + 1;
        cvt_i = (cvt_i == 2) ? 0 : cvt_i + 1;
    }

    // Epilogue: O /= l
    float* op = O + base;
    {
        float lall = l_own + __shfl_xor(l_own, 32);  // both halves of q=col
        float inv = 1.0f / lall;
        #pragma unroll
        for (int r = 0; r < 16; ++r) {
            int qrow = (r & 3) + 8 * (r >> 2) + 4 * h;
            float iq = __shfl(inv, qrow);
            op[(size_t)(qw + qrow) * DIM + col]      = of[0][r] * iq;
            op[(size_t)(qw + qrow) * DIM + 32 + col] = of[1][r] * iq;
        }
    }
}

extern "C" void kernel_launch(void* const* d_in, const int* in_sizes, int n_in,
                              void* d_out, int out_size, void* d_ws, size_t ws_size,
                              hipStream_t stream) {
    const float* Q = (const float*)d_in[0];
    const float* K = (const float*)d_in[1];
    const float* V = (const float*)d_in[2];
    float* Out = (float*)d_out;
    (void)d_ws; (void)ws_size;

    attn_fused<<<dim3(NH * (SEQ / 256)), dim3(512), 0, stream>>>(Q, K, V, Out);
}